// Round 15
// baseline (187.405 us; speedup 1.0000x reference)
//
#include <hip/hip_runtime.h>
#include <hip/hip_bf16.h>

typedef __attribute__((ext_vector_type(8))) short short8;
typedef __attribute__((ext_vector_type(4))) float f32x4;
typedef __attribute__((ext_vector_type(4))) int   i32x4;

#define NTOP 1000
#define KC   256
#define MROWS 40000
#define MBLK  64

static __device__ __forceinline__ unsigned short f2bf(float x) {
    union { float f; unsigned u; } v; v.f = x;
    unsigned r = (v.u + 0x7FFFu + ((v.u >> 16) & 1u)) >> 16;
    return (unsigned short)r;
}

// Kernel 1: colsum[j] += sum over an 8-row slab of nw. colsum pre-zeroed by memset.
__global__ void k_prep(const float* __restrict__ nw,
                       float* __restrict__ colsum) {
    int j  = blockIdx.x * 256 + threadIdx.x;
    int i0 = blockIdx.y * 8;
    if (j < NTOP) {
        float s = 0.f;
        int iend = min(i0 + 8, NTOP);
        for (int i = i0; i < iend; ++i) s += nw[(size_t)i * NTOP + j];
        atomicAdd(colsum + j, s);
    }
}

// Kernel 2: build B' in MFMA-fragment order (unchanged).
__global__ void k_vj(const float* __restrict__ V,
                     const float* __restrict__ noise,
                     const float* __restrict__ colsum,
                     unsigned short* __restrict__ Bp) {
    int t  = blockIdx.x * 256 + threadIdx.x;   // 0 .. 64*8*64-1 = 32767
    int nt = t >> 9;
    int s  = (t >> 6) & 7;
    int l  = t & 63;
    int lm = l & 15, lq = l >> 4;
    int n  = nt * 16 + lm;
    int k0 = s * 32 + lq * 8;
    union { short8 v; unsigned short us[8]; } pk;
    if (n < NTOP) {
        float cs = colsum[n];
        #pragma unroll
        for (int j = 0; j < 8; ++j) {
            int idx = n * KC + k0 + j;
            pk.us[j] = f2bf(V[idx] * cs + 0.1f * noise[idx]);
        }
    } else {
        #pragma unroll
        for (int j = 0; j < 8; ++j) pk.us[j] = 0;
    }
    reinterpret_cast<short8*>(Bp)[t] = pk.v;
}

// Kernel 2b: compress C -> row-major bitmask Cb[m][n/32] (5 MB). Proven.
__global__ __launch_bounds__(256) void k_cmask(const int* __restrict__ C,
                                               unsigned* __restrict__ Cb) {
    const int idx = blockIdx.x * 256 + threadIdx.x;   // < 40000*32 = 1,280,000
    const int m = idx >> 5, w = idx & 31;
    const int* p = C + (size_t)m * NTOP + w * 32;
    const int nbase = w * 32;
    unsigned word = 0;
    if (nbase + 32 <= NTOP) {
        #pragma unroll
        for (int j = 0; j < 32; j += 4) {
            i32x4 c4 = *reinterpret_cast<const i32x4*>(p + j);
            word |= (unsigned)(c4.x == 1) << (j + 0);
            word |= (unsigned)(c4.y == 1) << (j + 1);
            word |= (unsigned)(c4.z == 1) << (j + 2);
            word |= (unsigned)(c4.w == 1) << (j + 3);
        }
    } else {
        for (int j = 0; j < NTOP - nbase; ++j)
            word |= (unsigned)(p[j] == 1) << j;
    }
    Cb[idx] = word;
}

// ---- Scalarized pipeline macros: ONLY named variables, no arrays, no
//      pointer-taken state (the r7/r12/r13 spill trigger). ----

#define SBAR __builtin_amdgcn_sched_barrier(0)

#define LOADBF8(nt_, B0,B1,B2,B3,B4,B5,B6,B7) do {                        \
    const short8* bp_ = Bf + ((((nt_) * 8) << 6) + l);                    \
    B0 = bp_[0*64]; B1 = bp_[1*64]; B2 = bp_[2*64]; B3 = bp_[3*64];       \
    B4 = bp_[4*64]; B5 = bp_[5*64]; B6 = bp_[6*64]; B7 = bp_[7*64];       \
} while (0)

#define LOADIT8(nt_, R0,R1,R2,R3, W0,W1,W2,W3) do {                       \
    const int nst_ = ((nt_) << 4) + (lq << 2);                            \
    if (nst_ < NTOP) {                                                    \
        const int ws_ = nst_ >> 5;                                        \
        R0 = *reinterpret_cast<const f32x4*>(R + rb0 + nst_);             \
        R1 = *reinterpret_cast<const f32x4*>(R + rb1 + nst_);             \
        R2 = *reinterpret_cast<const f32x4*>(R + rb2 + nst_);             \
        R3 = *reinterpret_cast<const f32x4*>(R + rb3 + nst_);             \
        W0 = Cb[cb0 + ws_]; W1 = Cb[cb1 + ws_];                           \
        W2 = Cb[cb2 + ws_]; W3 = Cb[cb3 + ws_];                           \
    } else {                                                              \
        R0 = (f32x4){0.f,0.f,0.f,0.f}; R1 = (f32x4){0.f,0.f,0.f,0.f};     \
        R2 = (f32x4){0.f,0.f,0.f,0.f}; R3 = (f32x4){0.f,0.f,0.f,0.f};     \
        W0 = 0u; W1 = 0u; W2 = 0u; W3 = 0u;                               \
    }                                                                     \
} while (0)

#define MF1(s_, B_) do {                                                  \
    const short8 a0_ = Afrag[0][s_][l];                                   \
    const short8 a1_ = Afrag[1][s_][l];                                   \
    const short8 a2_ = Afrag[2][s_][l];                                   \
    const short8 a3_ = Afrag[3][s_][l];                                   \
    acc0 = __builtin_amdgcn_mfma_f32_16x16x32_bf16(B_, a0_, acc0, 0,0,0); \
    acc1 = __builtin_amdgcn_mfma_f32_16x16x32_bf16(B_, a1_, acc1, 0,0,0); \
    acc2 = __builtin_amdgcn_mfma_f32_16x16x32_bf16(B_, a2_, acc2, 0,0,0); \
    acc3 = __builtin_amdgcn_mfma_f32_16x16x32_bf16(B_, a3_, acc3, 0,0,0); \
} while (0)

#define MFMA8(B0,B1,B2,B3,B4,B5,B6,B7) do {                               \
    acc0 = (f32x4){0.f,0.f,0.f,0.f}; acc1 = (f32x4){0.f,0.f,0.f,0.f};     \
    acc2 = (f32x4){0.f,0.f,0.f,0.f}; acc3 = (f32x4){0.f,0.f,0.f,0.f};     \
    MF1(0,B0); MF1(1,B1); MF1(2,B2); MF1(3,B3);                           \
    MF1(4,B4); MF1(5,B5); MF1(6,B6); MF1(7,B7);                           \
} while (0)

#define EPI1(ACC, RV, W_, SH) do {                                        \
    const unsigned y_ = (W_) >> (SH);                                     \
    _Pragma("unroll")                                                     \
    for (int r_ = 0; r_ < 4; ++r_) {                                      \
        float muv_ = 1.f / (1.f + __expf(-ACC[r_]));                      \
        float d_   = RV[r_] - muv_;                                       \
        float lp_  = -50.f * d_ * d_ + 1.3836465597893728f;               \
        if ((y_ >> r_) & 1u) lpsum += lp_;                                \
    }                                                                     \
} while (0)

#define EPI8(R0,R1,R2,R3, W0,W1,W2,W3, SH) do {                           \
    EPI1(acc0, R0, W0, SH); EPI1(acc1, R1, W1, SH);                       \
    EPI1(acc2, R2, W2, SH); EPI1(acc3, R3, W3, SH);                       \
} while (0)

// Kernel 3: MBLK=64, 4x B-reuse, bitmask C, SCALARIZED PING-PONG pipeline:
// no end-of-iter buffer copies -> no per-iter vmcnt(0) drain (r14's 22k cy/iter
// was the drain paying full HBM latency each iter). Every load now has a full
// phase (~600-800cy) in flight; waiting on older loads never drains younger.
// launch_bounds(256,2): cap 256 VGPR -> spill structurally impossible (~150 live).
__global__ __launch_bounds__(256, 2) void k_main(
    const float* __restrict__ U, const float* __restrict__ w5,
    const float* __restrict__ b1, const short8* __restrict__ Bf,
    const float* __restrict__ R, const unsigned* __restrict__ Cb,
    float* __restrict__ out)
{
    __shared__ short8 Afrag[4][8][64];   // [mt][s][ll] : 32 KB
    __shared__ float  rawU[5120];        // 4 U-rows    : 20 KB

    const int tid  = threadIdx.x;
    const int wave = tid >> 6;
    const int l    = tid & 63;
    const int lm = l & 15;       // output m within 16-tile (col = lane&15)
    const int lq = l >> 4;       // quad: n-subblock of 4 (row = lq*4 + r)
    const int m0 = blockIdx.x * MBLK;

    const float w0 = w5[0], w1 = w5[1], w2 = w5[2], w3 = w5[3], w4 = w5[4];
    const float bb = b1[0];

    // ---- A-build: 16 groups of 4 rows (r14 verbatim, proven). ----
    const float* ub = U + (size_t)m0 * (KC * 5);
    for (int g = 0; g < 16; ++g) {
        const float* src = ub + (size_t)g * 5120;
        #pragma unroll
        for (int j = 0; j < 5; ++j) {
            const int idx = j * 1024 + tid * 4;
            *reinterpret_cast<f32x4*>(&rawU[idx]) =
                *reinterpret_cast<const f32x4*>(src + idx);
        }
        __syncthreads();
        if (tid < 128) {
            const int s   = tid >> 4;
            const int lqc = (tid >> 2) & 3;
            const int lmh = tid & 3;
            const int fi  = lmh * 1280 + s * 160 + lqc * 40;
            float u[40];
            #pragma unroll
            for (int i = 0; i < 10; ++i) {
                f32x4 t = *reinterpret_cast<const f32x4*>(&rawU[fi + i * 4]);
                u[i*4+0] = t.x; u[i*4+1] = t.y; u[i*4+2] = t.z; u[i*4+3] = t.w;
            }
            union { short8 v; unsigned short us[8]; } pk;
            #pragma unroll
            for (int j = 0; j < 8; ++j) {
                float e = u[j*5+0]*w0 + u[j*5+1]*w1 + u[j*5+2]*w2
                        + u[j*5+3]*w3 + u[j*5+4]*w4 + bb;
                pk.us[j] = f2bf(e);
            }
            const int mt = g >> 2;
            const int ll = lqc * 16 + ((g & 3) * 4 + lmh);
            Afrag[mt][s][ll] = pk.v;
        }
        __syncthreads();
    }

    // Per-lane fixed row bases (m = m0 + mt*16 + lm).
    const size_t rb0 = (size_t)(m0 +  0 + lm) * NTOP;
    const size_t rb1 = (size_t)(m0 + 16 + lm) * NTOP;
    const size_t rb2 = (size_t)(m0 + 32 + lm) * NTOP;
    const size_t rb3 = (size_t)(m0 + 48 + lm) * NTOP;
    const size_t cb0 = (size_t)(m0 +  0 + lm) * 32;
    const size_t cb1 = (size_t)(m0 + 16 + lm) * 32;
    const size_t cb2 = (size_t)(m0 + 32 + lm) * 32;
    const size_t cb3 = (size_t)(m0 + 48 + lm) * 32;

    float lpsum = 0.f;
    const int nt0 = wave << 4;        // this wave's first 16-col n-tile (even)
    const int shE = lq << 2;          // mask shift, even tiles
    const int shO = 16 + (lq << 2);   // mask shift, odd tiles

    // Ping-pong state: all individually named (no arrays anywhere).
    short8 pA0, pA1, pA2, pA3, pA4, pA5, pA6, pA7;   // Bf set A
    short8 pB0, pB1, pB2, pB3, pB4, pB5, pB6, pB7;   // Bf set B
    f32x4  rA0, rA1, rA2, rA3,  rB0, rB1, rB2, rB3;  // R sets
    unsigned wA0, wA1, wA2, wA3,  wB0, wB1, wB2, wB3; // mask sets
    f32x4  acc0, acc1, acc2, acc3;

    LOADBF8(nt0, pA0,pA1,pA2,pA3,pA4,pA5,pA6,pA7);
    LOADIT8(nt0, rA0,rA1,rA2,rA3, wA0,wA1,wA2,wA3);

    for (int it2 = 0; it2 < 8; ++it2) {
        const int ntE = nt0 + it2 * 2;

        // ---- EVEN phase: compute ntE from set A; prefetch ntE+1 into set B ----
        SBAR;
        LOADBF8(ntE + 1, pB0,pB1,pB2,pB3,pB4,pB5,pB6,pB7);
        SBAR;
        MFMA8(pA0,pA1,pA2,pA3,pA4,pA5,pA6,pA7);
        SBAR;
        LOADIT8(ntE + 1, rB0,rB1,rB2,rB3, wB0,wB1,wB2,wB3);
        SBAR;
        EPI8(rA0,rA1,rA2,rA3, wA0,wA1,wA2,wA3, shE);

        // ---- ODD phase: compute ntE+1 from set B; prefetch ntE+2 into set A ----
        SBAR;
        if (it2 < 7) { LOADBF8(ntE + 2, pA0,pA1,pA2,pA3,pA4,pA5,pA6,pA7); }
        SBAR;
        MFMA8(pB0,pB1,pB2,pB3,pB4,pB5,pB6,pB7);
        SBAR;
        if (it2 < 7) { LOADIT8(ntE + 2, rA0,rA1,rA2,rA3, wA0,wA1,wA2,wA3); }
        SBAR;
        EPI8(rB0,rB1,rB2,rB3, wB0,wB1,wB2,wB3, shO);
    }

    #pragma unroll
    for (int off = 32; off > 0; off >>= 1) lpsum += __shfl_down(lpsum, off);
    if (l == 0) atomicAdd(out, lpsum);
}

extern "C" void kernel_launch(void* const* d_in, const int* in_sizes, int n_in,
                              void* d_out, int out_size, void* d_ws, size_t ws_size,
                              hipStream_t stream) {
    const float* V     = (const float*)d_in[1];
    const float* R     = (const float*)d_in[2];
    const float* nw    = (const float*)d_in[3];
    const float* U     = (const float*)d_in[4];
    const float* w5    = (const float*)d_in[5];
    const float* b1    = (const float*)d_in[6];
    const float* noise = (const float*)d_in[7];
    const int*   C     = (const int*)d_in[8];
    float* out = (float*)d_out;

    // Workspace layout (ws >= 5.65 MB proven by r12-r14 passing runs):
    //   colsum: [0, 4000)         (padded to 8192)
    //   Bp    : [8192, 532480)    1024*256*2 = 524288 B
    //   Cb    : [532480, 5652480) 40000*32*4 = 5.12 MB
    float*          colsum = (float*)d_ws;
    unsigned short* Bp     = (unsigned short*)((char*)d_ws + 8192);
    unsigned*       Cb     = (unsigned*)((char*)d_ws + 532480);

    hipMemsetAsync(colsum, 0, NTOP * sizeof(float), stream);
    hipMemsetAsync(out, 0, sizeof(float), stream);
    hipLaunchKernelGGL(k_prep, dim3(4, 125), dim3(256), 0, stream, nw, colsum);
    hipLaunchKernelGGL(k_vj, dim3(128), dim3(256), 0, stream,
                       V, noise, colsum, Bp);
    hipLaunchKernelGGL(k_cmask, dim3(5000), dim3(256), 0, stream, C, Cb);
    hipLaunchKernelGGL(k_main, dim3(MROWS / MBLK), dim3(256), 0, stream,
                       U, w5, b1, (const short8*)Bp, R, Cb, out);
}

// Round 16
// 175.330 us; speedup vs baseline: 1.0689x; 1.0689x over previous
//
#include <hip/hip_runtime.h>
#include <hip/hip_bf16.h>

typedef __attribute__((ext_vector_type(8))) short short8;
typedef __attribute__((ext_vector_type(4))) float f32x4;
typedef __attribute__((ext_vector_type(4))) int   i32x4;
typedef __attribute__((ext_vector_type(4))) unsigned short us4;

#define NTOP 1000
#define KC   256
#define MROWS 40000
#define MBLK  64

static __device__ __forceinline__ unsigned short f2bf(float x) {
    union { float f; unsigned u; } v; v.f = x;
    unsigned r = (v.u + 0x7FFFu + ((v.u >> 16) & 1u)) >> 16;
    return (unsigned short)r;
}

// Kernel 1: colsum[j] += sum over an 8-row slab of nw. colsum pre-zeroed by memset.
__global__ void k_prep(const float* __restrict__ nw,
                       float* __restrict__ colsum) {
    int j  = blockIdx.x * 256 + threadIdx.x;
    int i0 = blockIdx.y * 8;
    if (j < NTOP) {
        float s = 0.f;
        int iend = min(i0 + 8, NTOP);
        for (int i = i0; i < iend; ++i) s += nw[(size_t)i * NTOP + j];
        atomicAdd(colsum + j, s);
    }
}

// Kernel 2: build B' in MFMA-fragment order (unchanged).
__global__ void k_vj(const float* __restrict__ V,
                     const float* __restrict__ noise,
                     const float* __restrict__ colsum,
                     unsigned short* __restrict__ Bp) {
    int t  = blockIdx.x * 256 + threadIdx.x;   // 0 .. 64*8*64-1 = 32767
    int nt = t >> 9;
    int s  = (t >> 6) & 7;
    int l  = t & 63;
    int lm = l & 15, lq = l >> 4;
    int n  = nt * 16 + lm;
    int k0 = s * 32 + lq * 8;
    union { short8 v; unsigned short us[8]; } pk;
    if (n < NTOP) {
        float cs = colsum[n];
        #pragma unroll
        for (int j = 0; j < 8; ++j) {
            int idx = n * KC + k0 + j;
            pk.us[j] = f2bf(V[idx] * cs + 0.1f * noise[idx]);
        }
    } else {
        #pragma unroll
        for (int j = 0; j < 8; ++j) pk.us[j] = 0;
    }
    reinterpret_cast<short8*>(Bp)[t] = pk.v;
}

// Kernel 2b: compress C -> row-major bitmask Cb[m][n/32] (5 MB). Proven.
__global__ __launch_bounds__(256) void k_cmask(const int* __restrict__ C,
                                               unsigned* __restrict__ Cb) {
    const int idx = blockIdx.x * 256 + threadIdx.x;   // < 40000*32 = 1,280,000
    const int m = idx >> 5, w = idx & 31;
    const int* p = C + (size_t)m * NTOP + w * 32;
    const int nbase = w * 32;
    unsigned word = 0;
    if (nbase + 32 <= NTOP) {
        #pragma unroll
        for (int j = 0; j < 32; j += 4) {
            i32x4 c4 = *reinterpret_cast<const i32x4*>(p + j);
            word |= (unsigned)(c4.x == 1) << (j + 0);
            word |= (unsigned)(c4.y == 1) << (j + 1);
            word |= (unsigned)(c4.z == 1) << (j + 2);
            word |= (unsigned)(c4.w == 1) << (j + 3);
        }
    } else {
        for (int j = 0; j < NTOP - nbase; ++j)
            word |= (unsigned)(p[j] == 1) << j;
    }
    Cb[idx] = word;
}

// Kernel 3: r14's main loop VERBATIM (proven best prof: 148us, no spill).
// A-BUILD OVERHAULED (the ~20-25us/dispatch serial prologue):
//  (a) stage-ahead: group g+1's loads issue before group g's compute (latency
//      hidden under compute instead of exposed per group),
//  (b) ALL 4 waves do frag compute (half-chunk split; r14 idled waves 2-3),
//  (c) rawU stride padded 1280->1284: kills the 4-way lmh bank conflict
//      (the 2.56M SQ_LDS_BANK_CONFLICT lives in A-build, not the main loop).
__global__ __launch_bounds__(256, 3) void k_main(
    const float* __restrict__ U, const float* __restrict__ w5,
    const float* __restrict__ b1, const short8* __restrict__ Bf,
    const float* __restrict__ R, const unsigned* __restrict__ Cb,
    float* __restrict__ out)
{
    __shared__ short8 Afrag[4][8][64];   // [mt][s][ll] : 32 KB
    __shared__ float  rawU[4 * 1284];    // 4 U-rows, padded : ~20.5 KB

    const int tid  = threadIdx.x;
    const int wave = tid >> 6;
    const int l    = tid & 63;
    const int lm = l & 15;       // output m within 16-tile (col = lane&15)
    const int lq = l >> 4;       // quad: n-subblock of 4 (row = lq*4 + r)
    const int m0 = blockIdx.x * MBLK;

    const float w0 = w5[0], w1 = w5[1], w2 = w5[2], w3 = w5[3], w4 = w5[4];
    const float bb = b1[0];

    // ---- A-build: 16 groups of 4 rows, pipelined, all-wave compute. ----
    {
        const float* ub = U + (size_t)m0 * (KC * 5);

        // Per-thread staging destinations (group-invariant): idx = j*1024+tid*4
        float* dst0; float* dst1; float* dst2; float* dst3; float* dst4;
        {
            int i0 = 0 * 1024 + tid * 4; dst0 = &rawU[(i0 / 1280) * 1284 + i0 % 1280];
            int i1 = 1 * 1024 + tid * 4; dst1 = &rawU[(i1 / 1280) * 1284 + i1 % 1280];
            int i2 = 2 * 1024 + tid * 4; dst2 = &rawU[(i2 / 1280) * 1284 + i2 % 1280];
            int i3 = 3 * 1024 + tid * 4; dst3 = &rawU[(i3 / 1280) * 1284 + i3 % 1280];
            int i4 = 4 * 1024 + tid * 4; dst4 = &rawU[(i4 / 1280) * 1284 + i4 % 1280];
        }
        // Per-thread frag-compute source (group-invariant): half-chunk split.
        const int chunk = tid >> 1;            // 0..127
        const int half  = tid & 1;             // 0..1 (outputs j = half*4 .. +3)
        const int s_c   = chunk >> 4;          // s-step 0..7
        const int lqc   = (chunk >> 2) & 3;
        const int lmh   = chunk & 3;
        const int fi    = lmh * 1284 + s_c * 160 + lqc * 40 + half * 20;

        f32x4 st0, st1, st2, st3, st4;
        st0 = *reinterpret_cast<const f32x4*>(ub + 0 * 1024 + tid * 4);
        st1 = *reinterpret_cast<const f32x4*>(ub + 1 * 1024 + tid * 4);
        st2 = *reinterpret_cast<const f32x4*>(ub + 2 * 1024 + tid * 4);
        st3 = *reinterpret_cast<const f32x4*>(ub + 3 * 1024 + tid * 4);
        st4 = *reinterpret_cast<const f32x4*>(ub + 4 * 1024 + tid * 4);

        for (int g = 0; g < 16; ++g) {
            *reinterpret_cast<f32x4*>(dst0) = st0;
            *reinterpret_cast<f32x4*>(dst1) = st1;
            *reinterpret_cast<f32x4*>(dst2) = st2;
            *reinterpret_cast<f32x4*>(dst3) = st3;
            *reinterpret_cast<f32x4*>(dst4) = st4;
            __syncthreads();

            // issue NEXT group's loads; latency hides under this group's compute
            if (g < 15) {
                const float* src = ub + (size_t)(g + 1) * 5120;
                st0 = *reinterpret_cast<const f32x4*>(src + 0 * 1024 + tid * 4);
                st1 = *reinterpret_cast<const f32x4*>(src + 1 * 1024 + tid * 4);
                st2 = *reinterpret_cast<const f32x4*>(src + 2 * 1024 + tid * 4);
                st3 = *reinterpret_cast<const f32x4*>(src + 3 * 1024 + tid * 4);
                st4 = *reinterpret_cast<const f32x4*>(src + 4 * 1024 + tid * 4);
            }

            // compute this thread's 4 outputs (half a chunk) from rawU
            {
                float u[20];
                #pragma unroll
                for (int i = 0; i < 5; ++i) {
                    f32x4 t = *reinterpret_cast<const f32x4*>(&rawU[fi + i * 4]);
                    u[i*4+0] = t.x; u[i*4+1] = t.y; u[i*4+2] = t.z; u[i*4+3] = t.w;
                }
                us4 pk;
                #pragma unroll
                for (int j = 0; j < 4; ++j) {
                    float e = u[j*5+0]*w0 + u[j*5+1]*w1 + u[j*5+2]*w2
                            + u[j*5+3]*w3 + u[j*5+4]*w4 + bb;
                    pk[j] = f2bf(e);
                }
                const int mt = g >> 2;
                const int ll = lqc * 16 + ((g & 3) * 4 + lmh);
                *reinterpret_cast<us4*>(
                    reinterpret_cast<unsigned short*>(&Afrag[mt][s_c][ll]) + half * 4) = pk;
            }
            __syncthreads();
        }
    }

    // Per-lane fixed row bases (m = m0 + mt*16 + lm).
    const size_t rb0 = (size_t)(m0 +  0 + lm) * NTOP;
    const size_t rb1 = (size_t)(m0 + 16 + lm) * NTOP;
    const size_t rb2 = (size_t)(m0 + 32 + lm) * NTOP;
    const size_t rb3 = (size_t)(m0 + 48 + lm) * NTOP;
    const size_t cb0 = (size_t)(m0 +  0 + lm) * 32;
    const size_t cb1 = (size_t)(m0 + 16 + lm) * 32;
    const size_t cb2 = (size_t)(m0 + 32 + lm) * 32;
    const size_t cb3 = (size_t)(m0 + 48 + lm) * 32;

    // Load R dwordx4 + mask words for one 16-col n-tile, all 4 m-tiles.
    auto LOADIT = [&](int nt16_, f32x4* rv_, unsigned* cw_) {
        const int nst = (nt16_ << 4) + (lq << 2);
        if (nst < NTOP) {
            const int ws = nst >> 5;
            rv_[0] = *reinterpret_cast<const f32x4*>(R + rb0 + nst);
            rv_[1] = *reinterpret_cast<const f32x4*>(R + rb1 + nst);
            rv_[2] = *reinterpret_cast<const f32x4*>(R + rb2 + nst);
            rv_[3] = *reinterpret_cast<const f32x4*>(R + rb3 + nst);
            cw_[0] = Cb[cb0 + ws];
            cw_[1] = Cb[cb1 + ws];
            cw_[2] = Cb[cb2 + ws];
            cw_[3] = Cb[cb3 + ws];
        } else {
            #pragma unroll
            for (int q = 0; q < 4; ++q) {
                rv_[q] = (f32x4){0.f, 0.f, 0.f, 0.f};
                cw_[q] = 0u;
            }
        }
    };

    // Load the 8 Bf fragments of one n-tile into registers.
    auto LOADBF = [&](int nt16_, short8* b_) {
        #pragma unroll
        for (int s = 0; s < 8; ++s)
            b_[s] = Bf[((nt16_ * 8 + s) << 6) + l];
    };

    float lpsum = 0.f;
    const int nt0 = wave << 4;   // this wave's first 16-col n-tile

    short8 bfc[8], bfn[8];
    f32x4 rv[4]; unsigned cw[4];
    LOADBF(nt0, bfc);
    LOADIT(nt0, rv, cw);

    for (int it = 0; it < 16; ++it) {
        const int nt16 = nt0 + it;

        // ---- pinned issue slot: NEXT n-tile's Bf (before this tile's MFMAs) ----
        __builtin_amdgcn_sched_barrier(0);
        if (it < 15) LOADBF(nt16 + 1, bfn);
        __builtin_amdgcn_sched_barrier(0);

        f32x4 acc[4];
        #pragma unroll
        for (int mt = 0; mt < 4; ++mt) acc[mt] = (f32x4){0.f, 0.f, 0.f, 0.f};

        #pragma unroll
        for (int s = 0; s < 8; ++s) {
            const short8 bfr = bfc[s];
            const short8 a0 = Afrag[0][s][l];
            const short8 a1 = Afrag[1][s][l];
            const short8 a2 = Afrag[2][s][l];
            const short8 a3 = Afrag[3][s][l];
            // swapped operands: bfr rows (n), A cols (m). One Bf load -> 4 MFMAs.
            acc[0] = __builtin_amdgcn_mfma_f32_16x16x32_bf16(bfr, a0, acc[0], 0, 0, 0);
            acc[1] = __builtin_amdgcn_mfma_f32_16x16x32_bf16(bfr, a1, acc[1], 0, 0, 0);
            acc[2] = __builtin_amdgcn_mfma_f32_16x16x32_bf16(bfr, a2, acc[2], 0, 0, 0);
            acc[3] = __builtin_amdgcn_mfma_f32_16x16x32_bf16(bfr, a3, acc[3], 0, 0, 0);
        }

        f32x4 rv2[4]; unsigned cw2[4];

        // ---- pinned issue slot: next n-tile's R/Cb ----
        __builtin_amdgcn_sched_barrier(0);
        if (it < 15) LOADIT(nt16 + 1, rv2, cw2);
        __builtin_amdgcn_sched_barrier(0);

        // Consume: n = nt16*16 + lq*4 + r, m = m0 + mt*16 + lm.
        const int sh = ((nt16 & 1) << 4) + (lq << 2);
        #pragma unroll
        for (int mt = 0; mt < 4; ++mt) {
            const unsigned y = cw[mt] >> sh;
            #pragma unroll
            for (int r = 0; r < 4; ++r) {
                float muv = 1.f / (1.f + __expf(-acc[mt][r]));
                float d   = rv[mt][r] - muv;
                float lp  = -50.f * d * d + 1.3836465597893728f;
                if ((y >> r) & 1u) lpsum += lp;
            }
        }

        if (it < 15) {
            #pragma unroll
            for (int s = 0; s < 8; ++s) bfc[s] = bfn[s];
            rv[0] = rv2[0]; cw[0] = cw2[0];
            rv[1] = rv2[1]; cw[1] = cw2[1];
            rv[2] = rv2[2]; cw[2] = cw2[2];
            rv[3] = rv2[3]; cw[3] = cw2[3];
        }
    }

    #pragma unroll
    for (int off = 32; off > 0; off >>= 1) lpsum += __shfl_down(lpsum, off);
    if (l == 0) atomicAdd(out, lpsum);
}

extern "C" void kernel_launch(void* const* d_in, const int* in_sizes, int n_in,
                              void* d_out, int out_size, void* d_ws, size_t ws_size,
                              hipStream_t stream) {
    const float* V     = (const float*)d_in[1];
    const float* R     = (const float*)d_in[2];
    const float* nw    = (const float*)d_in[3];
    const float* U     = (const float*)d_in[4];
    const float* w5    = (const float*)d_in[5];
    const float* b1    = (const float*)d_in[6];
    const float* noise = (const float*)d_in[7];
    const int*   C     = (const int*)d_in[8];
    float* out = (float*)d_out;

    // Workspace layout (ws >= 5.65 MB proven by r12-r15 passing runs):
    //   colsum: [0, 4000)         (padded to 8192)
    //   Bp    : [8192, 532480)    1024*256*2 = 524288 B
    //   Cb    : [532480, 5652480) 40000*32*4 = 5.12 MB
    float*          colsum = (float*)d_ws;
    unsigned short* Bp     = (unsigned short*)((char*)d_ws + 8192);
    unsigned*       Cb     = (unsigned*)((char*)d_ws + 532480);

    hipMemsetAsync(colsum, 0, NTOP * sizeof(float), stream);
    hipMemsetAsync(out, 0, sizeof(float), stream);
    hipLaunchKernelGGL(k_prep, dim3(4, 125), dim3(256), 0, stream, nw, colsum);
    hipLaunchKernelGGL(k_vj, dim3(128), dim3(256), 0, stream,
                       V, noise, colsum, Bp);
    hipLaunchKernelGGL(k_cmask, dim3(5000), dim3(256), 0, stream, C, Cb);
    hipLaunchKernelGGL(k_main, dim3(MROWS / MBLK), dim3(256), 0, stream,
                       U, w5, b1, (const short8*)Bp, R, Cb, out);
}